// Round 11
// baseline (991.883 us; speedup 1.0000x reference)
//
#include <hip/hip_runtime.h>

#define LOG2PI 1.837877f
#define LN2 0.6931471805599453f
#define RLN2 1.4426950408889634f
#define TRLN2 2.8853900817779268f   // 2/ln2 — key-domain scale (2x log2)
#define NLAB 46
#define NPAD 48           // children padded to 48 with poisoned carry rows
#define KK 4
#define LSEQ 512
#define KC 184            // KK*NLAB
#define BLOCK 832         // 13 waves: 12 A-waves + light emission wave 12
#define NA 736            // 46 parents * 16 lanes
#define EMB 768           // emission wave start
#define PADZ -1e30f       // pad-row z (plain domain): far below any real score

typedef float v2f __attribute__((ext_vector_type(2)));

__device__ __forceinline__ float fastrcp(float x){ return __builtin_amdgcn_rcpf(x); }
__device__ __forceinline__ float flog2(float x){ return __builtin_amdgcn_logf(x); }
__device__ __forceinline__ float fmed3(float a, float b, float c){
    return __builtin_amdgcn_fmed3f(a, b, c);
}
template<int CTRL>
__device__ __forceinline__ float dppq(float v){   // DPP exchange (VALU pipe)
    return __uint_as_float((unsigned)__builtin_amdgcn_mov_dpp(
        (int)__float_as_uint(v), CTRL, 0xF, 0xF, false));
}
template<int N> struct IC { static constexpr int value = N; };

__global__ __launch_bounds__(BLOCK, 4) void lveg_kernel(
    const int* __restrict__ tokens,
    const float* __restrict__ s_w_tab,
    const float* __restrict__ s_m_tab,
    const float* __restrict__ s_v_tab,
    const float* __restrict__ t_weight,
    const float* __restrict__ t_mu,
    const float* __restrict__ t_var_p,
    float* __restrict__ out)
{
    // carry per child c (row = 48B = 3 float4), dword layout:
    // [lam0,lam1, glam0,glam1, z0,z1, lam2,lam3, glam2,glam3, z2,z3]
    // (z entries stored PLAIN; key path scales by TRLN2 via fma;
    //  z slot holds score+z1+ez+sw — zm cancels algebraically)
    __shared__ float4 pkc4[2][NPAD][3];
    __shared__ float  scv[KC];           // raw final scores (nsc) for logsumexp
    __shared__ float  selb[192];         // survivor keys handoff (4 per parent)
    __shared__ float4 emi[2][NLAB];      // emission: sw+ez, 1/sv, sm/sv, 0
    __shared__ int    tokL[LSEQ];
    __shared__ float4 tabA[NLAB*NLAB];   // per-(c,p): e0, e1, invDetS, l11
    __shared__ float2 tabB[NLAB*NLAB];   // per-(c,p): l01, A'(=zeta1+0.5*LOG2PI+tw)

    const int b = blockIdx.x;
    const int tid = threadIdx.x;
    const int s = tid & 15;              // lane within 16-lane parent group
    const int p = tid >> 4;              // parent label 0..51
    const bool isA = (p < NLAB);

    // ---- one-time: phase-C constant tables into LDS + token preload ----
    for (int cp = tid; cp < NLAB*NLAB; cp += BLOCK) {
        float v0 = t_var_p[cp*3+0], v1 = t_var_p[cp*3+1], v2 = t_var_p[cp*3+2];
        float tm0 = t_mu[cp*2+0],  tm1 = t_mu[cp*2+1];
        float S00 = v0*v0 + v1*v1, S01 = v1*v2, S11 = v2*v2;
        float det = S00*S11 - S01*S01;
        float inv = 1.0f / det;
        float l00 = S11*inv, l01 = -S01*inv, l11 = S00*inv;
        float e0 = l00*tm0 + l01*tm1;
        float e1 = l01*tm0 + l11*tm1;
        float q1 = e0*(S00*e0 + S01*e1) + e1*(S01*e0 + S11*e1);
        float zeta1 = -0.5f*(2.0f*LOG2PI + __logf(det) + q1);
        tabA[cp] = make_float4(e0, e1, inv, l11);
        tabB[cp] = make_float2(l01, zeta1 + 0.5f*LOG2PI + t_weight[cp]);
    }
    for (int i = tid; i < LSEQ; i += BLOCK) tokL[i] = tokens[b*LSEQ + i];

    // ---- one-time: phase-A per-(c,p) constants as broadcast v2f pairs ----
    v2f bce0[3], bl11[3], binv[3], bl11s[3], bnqbs[3], bqes[3], bqcs[3], bAs2[3];
    if (isA) {
#pragma unroll
        for (int ci = 0; ci < 3; ++ci) {
            float ce0=0.f, cl11=0.f, cinv=1.f, cl11s=0.f, cnqbs=0.f,
                  cqes=0.f, cqcs=0.f, cAs2=0.f;
            int c = s + 16*ci;
            if (c < NLAB) {
                int cp = c*NLAB + p;
                float v0 = t_var_p[cp*3+0], v1 = t_var_p[cp*3+1], v2 = t_var_p[cp*3+2];
                float tm0 = t_mu[cp*2+0],  tm1 = t_mu[cp*2+1];
                float S00 = v0*v0 + v1*v1, S01 = v1*v2, S11 = v2*v2;
                float det = S00*S11 - S01*S01;
                float inv = 1.0f / det;
                float l00 = S11*inv, l01 = -S01*inv, l11 = S00*inv;
                float e0 = l00*tm0 + l01*tm1;
                float e1 = l01*tm0 + l11*tm1;
                float q1 = e0*(S00*e0 + S01*e1) + e1*(S01*e0 + S11*e1);
                float zeta1 = -0.5f*(2.0f*LOG2PI + __logf(det) + q1);
                ce0  = e0;
                cl11 = l11;
                cinv = inv;
                cl11s = l11 * RLN2;
                cnqbs = -(2.0f*l01*e1 * RLN2);       // negated: tA = em0*l11s + (-qbs)
                cqes = e1*e1 * RLN2;
                cqcs = l00*e1*e1 * RLN2;
                cAs2 = (zeta1 + LOG2PI + t_weight[cp]) * TRLN2;   // 2x key scale
            }
            bce0[ci].x=ce0;  bce0[ci].y=ce0;   bl11[ci].x=cl11;  bl11[ci].y=cl11;
            binv[ci].x=cinv; binv[ci].y=cinv;  bl11s[ci].x=cl11s;bl11s[ci].y=cl11s;
            bnqbs[ci].x=cnqbs;bnqbs[ci].y=cnqbs;bqes[ci].x=cqes; bqes[ci].y=cqes;
            bqcs[ci].x=cqcs; bqcs[ci].y=cqcs;  bAs2[ci].x=cAs2; bAs2[ci].y=cAs2;
        }
    }

    // ---- carry init from emission at position 0 (z stored PLAIN) ----
    if (tid < NLAB) {
        int tok0 = tokens[b * LSEQ];
        float sw  = s_w_tab[tok0*NLAB + tid];
        float sm  = s_m_tab[tok0*NLAB + tid];
        float svr = s_v_tab[tok0*NLAB + tid];
        float gv = svr*svr;
        float lam2 = 1.0f / gv;
        float glam = sm * lam2;
        float z2 = -0.5f*(LOG2PI + __logf(gv) + sm*glam);
        float zpad = -1e30f - 0.5f*LOG2PI;
        float4 fA; fA.x = lam2; fA.y = 1.0f; fA.z = glam; fA.w = 0.0f;
        float4 fB; fB.x = sw + z2; fB.y = zpad; fB.z = 1.0f; fB.w = 1.0f;
        float4 fC; fC.x = 0.0f; fC.y = 0.0f; fC.z = zpad; fC.w = zpad;
        pkc4[0][tid][0] = fA; pkc4[0][tid][1] = fB; pkc4[0][tid][2] = fC;
    } else if (tid < NPAD) {
        // poisoned pad rows 46,47 — written ONCE into BOTH buffers, never
        // rewritten (phase C only writes rows < 46). lam=1/glam=0 keep the
        // key math finite; z=PADZ makes the key ~-3e30 < any real key.
        float4 fA; fA.x = 1.0f; fA.y = 1.0f; fA.z = 0.0f; fA.w = 0.0f;
        float4 fB; fB.x = PADZ; fB.y = PADZ; fB.z = 1.0f; fB.w = 1.0f;
        float4 fC; fC.x = 0.0f; fC.y = 0.0f; fC.z = PADZ; fC.w = PADZ;
        pkc4[0][tid][0] = fA; pkc4[0][tid][1] = fB; pkc4[0][tid][2] = fC;
        pkc4[1][tid][0] = fA; pkc4[1][tid][1] = fB; pkc4[1][tid][2] = fC;
    }
    // ---- emission prefetch for t=1 (dedicated wave 12) ----
    if (tid >= EMB) {
        int pe = tid - EMB;
        if (pe < NLAB) {
            int tok = tokens[b*LSEQ + 1];
            float sw  = s_w_tab[tok*NLAB + pe];
            float sm  = s_m_tab[tok*NLAB + pe];
            float svr = s_v_tab[tok*NLAB + pe];
            float sv = svr*svr;
            float rs = 1.0f / sv;
            float eb = sm * rs;
            float ez = -0.5f*(LOG2PI + __logf(sv) + sm*eb);
            emi[1][pe] = make_float4(sw + ez, rs, eb, 0.0f);
        }
    }
    __syncthreads();

    // ================= the scan: 2 barriers per step =================
    auto stepf = [&](auto CC, auto FF, int t) {
        constexpr int CUR = decltype(CC)::value;
        constexpr bool FIN = (decltype(FF)::value != 0);
        if (isA) {
            // ---- upfront carry loads: 9 x ds_read_b128, pinned before compute ----
            float4 ld[3][3];
#pragma unroll
            for (int ci = 0; ci < 3; ++ci) {
                const float4* rp = &pkc4[CUR][s + 16*ci][0];
#pragma unroll
                for (int m = 0; m < 3; ++m) ld[ci][m] = rp[m];
            }
            __builtin_amdgcn_sched_barrier(0);
// key2 = Q*rdm + log2(rcp(dm)) + (zP*TRLN2 + rAs2)  [2x-scaled key; ordering
// preserved; -log2(dm) computed as log2(rdm) to reuse rdm with no negation]
#define KEYV(ci, LX, LY, GX, GY, ZX, ZY, OUTK)                                \
            v2f OUTK; {                                                       \
            v2f lamP;  lamP.x  = LX; lamP.y  = LY;                            \
            v2f glamP; glamP.x = GX; glamP.y = GY;                            \
            v2f zP;    zP.x    = ZX; zP.y    = ZY;                            \
            v2f em0 = glamP + bce0[ci];                                       \
            v2f dm  = lamP * bl11[ci] + binv[ci];                             \
            v2f tA  = em0 * bl11s[ci] + bnqbs[ci];                            \
            v2f tB  = lamP * bqes[ci] + bqcs[ci];                             \
            v2f Q   = em0 * tA + tB;                                          \
            v2f rdm; rdm.x = fastrcp(dm.x); rdm.y = fastrcp(dm.y);            \
            v2f lgr; lgr.x = flog2(rdm.x);  lgr.y = flog2(rdm.y);             \
            v2f base  = zP * TRLN2 + bAs2[ci];                                \
            OUTK = Q * rdm + base + lgr; }
#define PK(kf, id) __uint_as_float((__float_as_uint(kf) & 0xFFFFFF00u) | (unsigned)(id))
            // ---- ci=0: 4 keys, specialized exact inserts (no NEGINF init) ----
            KEYV(0, ld[0][0].x, ld[0][0].y, ld[0][0].z, ld[0][0].w, ld[0][1].x, ld[0][1].y, k00)
            KEYV(0, ld[0][1].z, ld[0][1].w, ld[0][2].x, ld[0][2].y, ld[0][2].z, ld[0][2].w, k01)
            float a0 = PK(k00.x, 0*NLAB + s);
            float a1 = PK(k00.y, 1*NLAB + s);
            float a2 = PK(k01.x, 2*NLAB + s);
            float a3 = PK(k01.y, 3*NLAB + s);
            float t0 = fmaxf(a0, a1), t1 = fminf(a0, a1);     // 2-list
            float n0 = fmaxf(t0, a2), n1 = fmed3(a2, t0, t1); // insert -> 3-list
            float t2 = fminf(t1, a2); t0 = n0; t1 = n1;
            n0 = fmaxf(t0, a3); n1 = fmed3(a3, t0, t1);       // insert -> 4-list
            float n2 = fmed3(a3, t1, t2);
            float t3 = fminf(t2, a3); t0 = n0; t1 = n1; t2 = n2;
            // ---- ci=1,2: full insert network ----
#define INS(kf, id) {                                                         \
            float fk = PK(kf, id);                                            \
            float m0 = fmaxf(t0, fk);                                         \
            float m1 = fmed3(fk, t0, t1);                                     \
            float m2 = fmed3(fk, t1, t2);                                     \
            float m3 = fmed3(fk, t2, t3);                                     \
            t0=m0; t1=m1; t2=m2; t3=m3; }
#define CANDP(ci, pr, LX, LY, GX, GY, ZX, ZY) {                               \
            KEYV(ci, LX, LY, GX, GY, ZX, ZY, kk)                              \
            INS(kk.x, (2*(pr))*NLAB   + s + 16*(ci))                          \
            INS(kk.y, (2*(pr)+1)*NLAB + s + 16*(ci)) }
            CANDP(1, 0, ld[1][0].x, ld[1][0].y, ld[1][0].z, ld[1][0].w, ld[1][1].x, ld[1][1].y)
            CANDP(1, 1, ld[1][1].z, ld[1][1].w, ld[1][2].x, ld[1][2].y, ld[1][2].z, ld[1][2].w)
            CANDP(2, 0, ld[2][0].x, ld[2][0].y, ld[2][0].z, ld[2][0].w, ld[2][1].x, ld[2][1].y)
            CANDP(2, 1, ld[2][1].z, ld[2][1].w, ld[2][2].x, ld[2][2].y, ld[2][2].z, ld[2][2].w)
#undef CANDP
#undef INS
#undef PK
#undef KEYV
            // ---- merge across 16-lane group: ALL-DPP (VALU pipe only) ----
            // After xor1+xor2 each aligned 4-group holds an identical sorted
            // list; stage 3 needs ANY cross-quad pairing in the 8-group
            // (ROW_HALF_MIRROR), stage 4 any cross-8 pairing (row_ror:8),
            // final stage set-only.
#define MSTAGE(F) { float b0=F(t0), b1=F(t1), b2=F(t2), b3=F(t3);                 \
                float M0=fmaxf(t0,b3), M1=fmaxf(t1,b2), M2=fmaxf(t2,b1), M3=fmaxf(t3,b0); \
                float x;                                                          \
                x=fmaxf(M0,M2); M2=fminf(M0,M2); M0=x;  x=fmaxf(M1,M3); M3=fminf(M1,M3); M1=x; \
                x=fmaxf(M0,M1); M1=fminf(M0,M1); M0=x;  x=fmaxf(M2,M3); M3=fminf(M2,M3); M2=x; \
                t0=M0; t1=M1; t2=M2; t3=M3; }
            MSTAGE(dppq<0xB1>)      // xor 1 (quad_perm)
            MSTAGE(dppq<0x4E>)      // xor 2 (quad_perm)
            MSTAGE(dppq<0x141>)     // cross-4 pairing (ROW_HALF_MIRROR)
            {   // final stage: cross-8 pairing (row_ror:8), set-only
                float b0=dppq<0x128>(t0), b1=dppq<0x128>(t1),
                      b2=dppq<0x128>(t2), b3=dppq<0x128>(t3);
                float M0=fmaxf(t0,b3), M1=fmaxf(t1,b2), M2=fmaxf(t2,b1), M3=fmaxf(t3,b0);
                t0=M0; t1=M1; t2=M2; t3=M3;
            }
#undef MSTAGE
            // ---- survivor handoff: 4 lanes/group dump packed keys to LDS ----
            if (s < 4) {
                float sel = (s==0)?t0 : (s==1)?t1 : (s==2)?t2 : t3;
                selb[4*p + s] = sel;
            }
        } else if (tid >= EMB) {
            // ---- emission prefetch for step t+1 into emi[CUR] (wave 12) ----
            int pe = tid - EMB;
            if (pe < NLAB && t + 1 < LSEQ) {
                int tok = tokL[t + 1];
                float sw  = s_w_tab[tok*NLAB + pe];
                float sm  = s_m_tab[tok*NLAB + pe];
                float svr = s_v_tab[tok*NLAB + pe];
                float sv = svr*svr;
                float rs = 1.0f / sv;
                float eb = sm * rs;
                float ez = -0.5f*(LOG2PI + __logf(sv) + sm*eb);
                emi[CUR][pe] = make_float4(sw + ez, rs, eb, 0.0f);
            }
        }
        __syncthreads();   // barrier 1: selection done, survivors in selb
        // ---- phase C, COMPACT: waves 0-3 (one per SIMD), 46 tasks each ----
        // Recompute survivor score exactly + multiply next emission gaussian.
        // ln(var2) = ln(lm00) - ln(dm) makes the ln(dm) in score+z1 cancel;
        // the stored z-carry is score+z1+ez+sw (zm cancels), so the
        // whole vm/zm/nsc block is FIN-only.
        if (tid < 256) {
            int l = tid & 63;
            if (l < NLAB) {
                int j  = (tid >> 6) * NLAB + l;       // 4 waves x 46 = 184 tasks
                int pp = j >> 2;                      // parent label
                int ss = j & 3;                       // survivor slot
                float4 ev = emi[CUR ^ 1][pp];         // independent of sel: load first
                float sel = selb[j];
                unsigned kc = __float_as_uint(sel) & 0xFFu;
                unsigned k  = (kc * 1428u) >> 16;
                int c  = (int)kc - (int)k*NLAB;
                int cp = c*NLAB + pp;
                float4 ta = tabA[cp];                 // e0,e1,inv,l11
                float2 tb = tabB[cp];                 // l01, A' = zeta1+0.5*LOG2PI+tw
                const float* sp = (const float*)&pkc4[CUR][c][0]
                                  + 6*(int)(k >> 1) + (int)(k & 1);
                float lam2 = sp[0];
                float glam = sp[2];
                float z2s  = sp[4];                   // plain domain now
                float em0 = ta.x + glam;
                float em1 = ta.y;
                float l01 = tb.x;
                float dm  = fmaf(lam2, ta.w, ta.z);
                float rdm = fastrcp(dm);
                float lm00 = fmaf(l01, l01, dm) * fastrcp(ta.w);  // l00 + lam2
                float Q = fmaf(em0, fmaf(ta.w, em0, -2.0f*l01*em1), lm00*em1*em1);
                float mu2  = rdm*(lm00*em1 - l01*em0);
                float rlm  = fastrcp(lm00);
                float rv1  = dm * rlm;                // 1/var2
                float lnlm = __logf(lm00);
                float lam = rv1 + ev.y;
                float emm = fmaf(mu2, rv1, ev.z);
                float sz  = fmaf(0.5f, fmaf(Q, rdm, -fmaf(mu2*mu2, rv1, lnlm)),
                                 tb.y + z2s + ev.x);
                float* wp = (float*)&pkc4[CUR ^ 1][pp][0] + 6*(ss >> 1) + (ss & 1);
                wp[0] = lam;
                wp[2] = emm;
                wp[4] = sz;                           // plain domain
                if (FIN) {
                    float vm = fastrcp(lam);
                    float zm = -0.5f*(LOG2PI + __logf(vm) + emm*emm*vm);
                    scv[ss*NLAB + pp] = sz - zm;      // nsc, feeds logsumexp
                }
            }
        }
        __syncthreads();   // barrier 2: new carries visible to all waves
    };

    int t = 1;
#pragma unroll 1
    for (int it = 0; it < (LSEQ - 2) / 2; ++it) {   // 255 double-steps: t=1..510
        stepf(IC<0>{}, IC<0>{}, t); ++t;
        stepf(IC<1>{}, IC<0>{}, t); ++t;
    }
    stepf(IC<0>{}, IC<1>{}, t);   // t = 511 (FIN: computes zm/nsc -> scv)

    // ---- final logsumexp over 184 component scores (wave 0) ----
    if (tid < 64) {
        float mx = -1e38f;
        for (int i = tid; i < KC; i += 64) mx = fmaxf(mx, scv[i]);
#pragma unroll
        for (int m = 32; m; m >>= 1) mx = fmaxf(mx, __shfl_xor(mx, m, 64));
        float sum = 0.0f;
        for (int i = tid; i < KC; i += 64) sum += __expf(scv[i] - mx);
#pragma unroll
        for (int m = 32; m; m >>= 1) sum += __shfl_xor(sum, m, 64);
        if (tid == 0) out[b] = mx + __logf(sum);
    }
}

extern "C" void kernel_launch(void* const* d_in, const int* in_sizes, int n_in,
                              void* d_out, int out_size, void* d_ws, size_t ws_size,
                              hipStream_t stream) {
    const int*   tokens = (const int*)d_in[0];
    const float* sw     = (const float*)d_in[1];
    const float* sm     = (const float*)d_in[2];
    const float* sv     = (const float*)d_in[3];
    const float* tw     = (const float*)d_in[4];
    const float* tmu    = (const float*)d_in[5];
    const float* tvp    = (const float*)d_in[6];
    float* o = (float*)d_out;
    hipLaunchKernelGGL(lveg_kernel, dim3(64), dim3(BLOCK), 0, stream,
                       tokens, sw, sm, sv, tw, tmu, tvp, o);
}

// Round 12
// 979.175 us; speedup vs baseline: 1.0130x; 1.0130x over previous
//
#include <hip/hip_runtime.h>

#define LOG2PI 1.837877f
#define LN2 0.6931471805599453f
#define RLN2 1.4426950408889634f
#define TRLN2 2.8853900817779268f   // 2/ln2 — key-domain scale (2x log2)
#define HLN2 0.34657359027997264f   // ln2/2 — inverse for phase-C z readback
#define NLAB 46
#define NPAD 48           // children padded to 48 with poisoned carry rows
#define KK 4
#define LSEQ 512
#define KC 184            // KK*NLAB
#define BLOCK 832         // 13 waves: 12 A-waves + light emission wave 12
#define NA 736            // 46 parents * 16 lanes
#define EMB 768           // emission wave start
#define PADZ -1e37f       // pad-row z: finite, below every real key, no NaN on pack

typedef float v2f __attribute__((ext_vector_type(2)));

__device__ __forceinline__ float fastrcp(float x){ return __builtin_amdgcn_rcpf(x); }
__device__ __forceinline__ float flog2(float x){ return __builtin_amdgcn_logf(x); }
__device__ __forceinline__ float fmed3(float a, float b, float c){
    return __builtin_amdgcn_fmed3f(a, b, c);
}
template<int CTRL>
__device__ __forceinline__ float dppq(float v){   // DPP exchange (VALU pipe)
    return __uint_as_float((unsigned)__builtin_amdgcn_mov_dpp(
        (int)__float_as_uint(v), CTRL, 0xF, 0xF, false));
}
template<int N> struct IC { static constexpr int value = N; };

__global__ __launch_bounds__(BLOCK, 4) void lveg_kernel(
    const int* __restrict__ tokens,
    const float* __restrict__ s_w_tab,
    const float* __restrict__ s_m_tab,
    const float* __restrict__ s_v_tab,
    const float* __restrict__ t_weight,
    const float* __restrict__ t_mu,
    const float* __restrict__ t_var_p,
    float* __restrict__ out)
{
    // carry per child c (row = 48B = 3 float4), dword layout:
    // [lam0,lam1, glam0,glam1, z0,z1, lam2,lam3, glam2,glam3, z2,z3]
    // (z entries stored scaled by TRLN2 = 2/ln2 for the selection key path;
    //  z slot holds (score+z1+ez+sw)*TRLN2 — zm cancels algebraically)
    __shared__ float4 pkc4[2][NPAD][3];
    __shared__ float  scv[KC];           // raw final scores (nsc) for logsumexp
    __shared__ float  selb[192];         // survivor keys handoff (4 per parent)
    __shared__ float4 emi[2][NLAB];      // emission: sw+ez, 1/sv, sm/sv, 0
    __shared__ int    tokL[LSEQ];
    __shared__ float4 tabA[NLAB*NLAB];   // per-(c,p): e0, e1, invDetS, l11
    __shared__ float2 tabB[NLAB*NLAB];   // per-(c,p): l01, A'(=zeta1+0.5*LOG2PI+tw)

    const int b = blockIdx.x;
    const int tid = threadIdx.x;
    const int s = tid & 15;              // lane within 16-lane parent group
    const int p = tid >> 4;              // parent label 0..51
    const bool isA = (p < NLAB);

    // ---- one-time: phase-C constant tables into LDS + token preload ----
    for (int cp = tid; cp < NLAB*NLAB; cp += BLOCK) {
        float v0 = t_var_p[cp*3+0], v1 = t_var_p[cp*3+1], v2 = t_var_p[cp*3+2];
        float tm0 = t_mu[cp*2+0],  tm1 = t_mu[cp*2+1];
        float S00 = v0*v0 + v1*v1, S01 = v1*v2, S11 = v2*v2;
        float det = S00*S11 - S01*S01;
        float inv = 1.0f / det;
        float l00 = S11*inv, l01 = -S01*inv, l11 = S00*inv;
        float e0 = l00*tm0 + l01*tm1;
        float e1 = l01*tm0 + l11*tm1;
        float q1 = e0*(S00*e0 + S01*e1) + e1*(S01*e0 + S11*e1);
        float zeta1 = -0.5f*(2.0f*LOG2PI + __logf(det) + q1);
        tabA[cp] = make_float4(e0, e1, inv, l11);
        tabB[cp] = make_float2(l01, zeta1 + 0.5f*LOG2PI + t_weight[cp]);
    }
    for (int i = tid; i < LSEQ; i += BLOCK) tokL[i] = tokens[b*LSEQ + i];

    // ---- one-time: phase-A per-(c,p) constants as broadcast v2f pairs ----
    v2f bce0[3], bl11[3], binv[3], bl11s[3], bnqbs[3], bqes[3], bqcs[3], bAs2[3];
    if (isA) {
#pragma unroll
        for (int ci = 0; ci < 3; ++ci) {
            float ce0=0.f, cl11=0.f, cinv=1.f, cl11s=0.f, cnqbs=0.f,
                  cqes=0.f, cqcs=0.f, cAs2=0.f;
            int c = s + 16*ci;
            if (c < NLAB) {
                int cp = c*NLAB + p;
                float v0 = t_var_p[cp*3+0], v1 = t_var_p[cp*3+1], v2 = t_var_p[cp*3+2];
                float tm0 = t_mu[cp*2+0],  tm1 = t_mu[cp*2+1];
                float S00 = v0*v0 + v1*v1, S01 = v1*v2, S11 = v2*v2;
                float det = S00*S11 - S01*S01;
                float inv = 1.0f / det;
                float l00 = S11*inv, l01 = -S01*inv, l11 = S00*inv;
                float e0 = l00*tm0 + l01*tm1;
                float e1 = l01*tm0 + l11*tm1;
                float q1 = e0*(S00*e0 + S01*e1) + e1*(S01*e0 + S11*e1);
                float zeta1 = -0.5f*(2.0f*LOG2PI + __logf(det) + q1);
                ce0  = e0;
                cl11 = l11;
                cinv = inv;
                cl11s = l11 * RLN2;
                cnqbs = -(2.0f*l01*e1 * RLN2);       // negated: tA = em0*l11s + (-qbs)
                cqes = e1*e1 * RLN2;
                cqcs = l00*e1*e1 * RLN2;
                cAs2 = (zeta1 + LOG2PI + t_weight[cp]) * TRLN2;   // 2x key scale
            }
            bce0[ci].x=ce0;  bce0[ci].y=ce0;   bl11[ci].x=cl11;  bl11[ci].y=cl11;
            binv[ci].x=cinv; binv[ci].y=cinv;  bl11s[ci].x=cl11s;bl11s[ci].y=cl11s;
            bnqbs[ci].x=cnqbs;bnqbs[ci].y=cnqbs;bqes[ci].x=cqes; bqes[ci].y=cqes;
            bqcs[ci].x=cqcs; bqcs[ci].y=cqcs;  bAs2[ci].x=cAs2; bAs2[ci].y=cAs2;
        }
    }

    // ---- carry init from emission at position 0 ----
    if (tid < NLAB) {
        int tok0 = tokens[b * LSEQ];
        float sw  = s_w_tab[tok0*NLAB + tid];
        float sm  = s_m_tab[tok0*NLAB + tid];
        float svr = s_v_tab[tok0*NLAB + tid];
        float gv = svr*svr;
        float lam2 = 1.0f / gv;
        float glam = sm * lam2;
        float z2 = -0.5f*(LOG2PI + __logf(gv) + sm*glam);
        float zpad = (-1e30f - 0.5f*LOG2PI) * TRLN2;
        float4 fA; fA.x = lam2; fA.y = 1.0f; fA.z = glam; fA.w = 0.0f;
        float4 fB; fB.x = (sw + z2)*TRLN2; fB.y = zpad; fB.z = 1.0f; fB.w = 1.0f;
        float4 fC; fC.x = 0.0f; fC.y = 0.0f; fC.z = zpad; fC.w = zpad;
        pkc4[0][tid][0] = fA; pkc4[0][tid][1] = fB; pkc4[0][tid][2] = fC;
    } else if (tid < NPAD) {
        // poisoned pad rows 46,47 — written ONCE into BOTH buffers, never
        // rewritten (phase C only writes rows < 46). lam=1/glam=0 keep the
        // key math finite; z=PADZ makes the key ~-2e37 < any real key.
        float4 fA; fA.x = 1.0f; fA.y = 1.0f; fA.z = 0.0f; fA.w = 0.0f;
        float4 fB; fB.x = PADZ; fB.y = PADZ; fB.z = 1.0f; fB.w = 1.0f;
        float4 fC; fC.x = 0.0f; fC.y = 0.0f; fC.z = PADZ; fC.w = PADZ;
        pkc4[0][tid][0] = fA; pkc4[0][tid][1] = fB; pkc4[0][tid][2] = fC;
        pkc4[1][tid][0] = fA; pkc4[1][tid][1] = fB; pkc4[1][tid][2] = fC;
    }
    // ---- emission prefetch for t=1 (dedicated wave 12) ----
    if (tid >= EMB) {
        int pe = tid - EMB;
        if (pe < NLAB) {
            int tok = tokens[b*LSEQ + 1];
            float sw  = s_w_tab[tok*NLAB + pe];
            float sm  = s_m_tab[tok*NLAB + pe];
            float svr = s_v_tab[tok*NLAB + pe];
            float sv = svr*svr;
            float rs = 1.0f / sv;
            float eb = sm * rs;
            float ez = -0.5f*(LOG2PI + __logf(sv) + sm*eb);
            emi[1][pe] = make_float4(sw + ez, rs, eb, 0.0f);
        }
    }
    __syncthreads();

    // ================= the scan: 2 barriers per step =================
    auto stepf = [&](auto CC, auto FF, int t) {
        constexpr int CUR = decltype(CC)::value;
        constexpr bool FIN = (decltype(FF)::value != 0);
        if (isA) {
            // ---- upfront carry loads: 9 x ds_read_b128, pinned before compute ----
            float4 ld[3][3];
#pragma unroll
            for (int ci = 0; ci < 3; ++ci) {
                const float4* rp = &pkc4[CUR][s + 16*ci][0];
#pragma unroll
                for (int m = 0; m < 3; ++m) ld[ci][m] = rp[m];
            }
            __builtin_amdgcn_sched_barrier(0);
// key2 = Q*rdm + log2(rcp(dm)) + (zP2 + rAs2)   [= 2x the old key; ordering
// preserved; -log2(dm) computed as log2(rdm) to reuse rdm with no negation]
#define KEYV(ci, LX, LY, GX, GY, ZX, ZY, OUTK)                                \
            v2f OUTK; {                                                       \
            v2f lamP;  lamP.x  = LX; lamP.y  = LY;                            \
            v2f glamP; glamP.x = GX; glamP.y = GY;                            \
            v2f zP;    zP.x    = ZX; zP.y    = ZY;                            \
            v2f em0 = glamP + bce0[ci];                                       \
            v2f dm  = lamP * bl11[ci] + binv[ci];                             \
            v2f tA  = em0 * bl11s[ci] + bnqbs[ci];                            \
            v2f tB  = lamP * bqes[ci] + bqcs[ci];                             \
            v2f Q   = em0 * tA + tB;                                          \
            v2f rdm; rdm.x = fastrcp(dm.x); rdm.y = fastrcp(dm.y);            \
            v2f lgr; lgr.x = flog2(rdm.x);  lgr.y = flog2(rdm.y);             \
            v2f base  = zP + bAs2[ci];                                        \
            OUTK = Q * rdm + base + lgr; }
#define PK(kf, id) __uint_as_float((__float_as_uint(kf) & 0xFFFFFF00u) | (unsigned)(id))
            // ---- ci=0: 4 keys, specialized exact inserts (no NEGINF init) ----
            KEYV(0, ld[0][0].x, ld[0][0].y, ld[0][0].z, ld[0][0].w, ld[0][1].x, ld[0][1].y, k00)
            KEYV(0, ld[0][1].z, ld[0][1].w, ld[0][2].x, ld[0][2].y, ld[0][2].z, ld[0][2].w, k01)
            float a0 = PK(k00.x, 0*NLAB + s);
            float a1 = PK(k00.y, 1*NLAB + s);
            float a2 = PK(k01.x, 2*NLAB + s);
            float a3 = PK(k01.y, 3*NLAB + s);
            float t0 = fmaxf(a0, a1), t1 = fminf(a0, a1);     // 2-list
            float n0 = fmaxf(t0, a2), n1 = fmed3(a2, t0, t1); // insert -> 3-list
            float t2 = fminf(t1, a2); t0 = n0; t1 = n1;
            n0 = fmaxf(t0, a3); n1 = fmed3(a3, t0, t1);       // insert -> 4-list
            float n2 = fmed3(a3, t1, t2);
            float t3 = fminf(t2, a3); t0 = n0; t1 = n1; t2 = n2;
            // ---- ci=1,2: full insert network ----
#define INS(kf, id) {                                                         \
            float fk = PK(kf, id);                                            \
            float m0 = fmaxf(t0, fk);                                         \
            float m1 = fmed3(fk, t0, t1);                                     \
            float m2 = fmed3(fk, t1, t2);                                     \
            float m3 = fmed3(fk, t2, t3);                                     \
            t0=m0; t1=m1; t2=m2; t3=m3; }
#define CANDP(ci, pr, LX, LY, GX, GY, ZX, ZY) {                               \
            KEYV(ci, LX, LY, GX, GY, ZX, ZY, kk)                              \
            INS(kk.x, (2*(pr))*NLAB   + s + 16*(ci))                          \
            INS(kk.y, (2*(pr)+1)*NLAB + s + 16*(ci)) }
            CANDP(1, 0, ld[1][0].x, ld[1][0].y, ld[1][0].z, ld[1][0].w, ld[1][1].x, ld[1][1].y)
            CANDP(1, 1, ld[1][1].z, ld[1][1].w, ld[1][2].x, ld[1][2].y, ld[1][2].z, ld[1][2].w)
            CANDP(2, 0, ld[2][0].x, ld[2][0].y, ld[2][0].z, ld[2][0].w, ld[2][1].x, ld[2][1].y)
            CANDP(2, 1, ld[2][1].z, ld[2][1].w, ld[2][2].x, ld[2][2].y, ld[2][2].z, ld[2][2].w)
#undef CANDP
#undef INS
#undef PK
#undef KEYV
            // ---- merge across 16-lane group: ALL-DPP (VALU pipe only) ----
            // After xor1+xor2 each aligned 4-group holds an identical sorted
            // list; stage 3 needs ANY cross-quad pairing in the 8-group
            // (ROW_HALF_MIRROR), stage 4 any cross-8 pairing (row_ror:8),
            // final stage set-only.
#define MSTAGE(F) { float b0=F(t0), b1=F(t1), b2=F(t2), b3=F(t3);                 \
                float M0=fmaxf(t0,b3), M1=fmaxf(t1,b2), M2=fmaxf(t2,b1), M3=fmaxf(t3,b0); \
                float x;                                                          \
                x=fmaxf(M0,M2); M2=fminf(M0,M2); M0=x;  x=fmaxf(M1,M3); M3=fminf(M1,M3); M1=x; \
                x=fmaxf(M0,M1); M1=fminf(M0,M1); M0=x;  x=fmaxf(M2,M3); M3=fminf(M2,M3); M2=x; \
                t0=M0; t1=M1; t2=M2; t3=M3; }
            MSTAGE(dppq<0xB1>)      // xor 1 (quad_perm)
            MSTAGE(dppq<0x4E>)      // xor 2 (quad_perm)
            MSTAGE(dppq<0x141>)     // cross-4 pairing (ROW_HALF_MIRROR)
            {   // final stage: cross-8 pairing (row_ror:8), set-only
                float b0=dppq<0x128>(t0), b1=dppq<0x128>(t1),
                      b2=dppq<0x128>(t2), b3=dppq<0x128>(t3);
                float M0=fmaxf(t0,b3), M1=fmaxf(t1,b2), M2=fmaxf(t2,b1), M3=fmaxf(t3,b0);
                t0=M0; t1=M1; t2=M2; t3=M3;
            }
#undef MSTAGE
            // ---- survivor handoff: 4 lanes/group dump packed keys to LDS ----
            if (s < 4) {
                float sel = (s==0)?t0 : (s==1)?t1 : (s==2)?t2 : t3;
                selb[4*p + s] = sel;
            }
        } else if (tid >= EMB) {
            // ---- emission prefetch for step t+1 into emi[CUR] (wave 12) ----
            int pe = tid - EMB;
            if (pe < NLAB && t + 1 < LSEQ) {
                int tok = tokL[t + 1];
                float sw  = s_w_tab[tok*NLAB + pe];
                float sm  = s_m_tab[tok*NLAB + pe];
                float svr = s_v_tab[tok*NLAB + pe];
                float sv = svr*svr;
                float rs = 1.0f / sv;
                float eb = sm * rs;
                float ez = -0.5f*(LOG2PI + __logf(sv) + sm*eb);
                emi[CUR][pe] = make_float4(sw + ez, rs, eb, 0.0f);
            }
        }
        __syncthreads();   // barrier 1: selection done, survivors in selb
        // ---- phase C, COMPACT: waves 0-2 (one per SIMD), 184 dense tasks ----
        // Recompute survivor score exactly + multiply next emission gaussian.
        // ln(var2) = ln(lm00) - ln(dm) makes the ln(dm) in score+z1 cancel;
        // the stored z-carry is (score+z1+ez+sw)*TRLN2 (zm cancels), so the
        // whole vm/zm/nsc block is FIN-only.
        if (tid < 192) {
            int j = tid;
            if (j < KC) {
                float sel = selb[j];
                int pp = j >> 2;                      // parent label
                int ss = j & 3;                       // survivor slot
                unsigned kc = __float_as_uint(sel) & 0xFFu;
                unsigned k  = (kc * 1428u) >> 16;
                int c  = (int)kc - (int)k*NLAB;
                int cp = c*NLAB + pp;
                float4 ta = tabA[cp];                 // e0,e1,inv,l11
                float2 tb = tabB[cp];                 // l01, A' = zeta1+0.5*LOG2PI+tw
                const float* sp = (const float*)&pkc4[CUR][c][0]
                                  + 6*(int)(k >> 1) + (int)(k & 1);
                float lam2 = sp[0];
                float glam = sp[2];
                float z2s  = sp[4] * HLN2;            // undo TRLN2 key scale
                float em0 = ta.x + glam;
                float em1 = ta.y;
                float l01 = tb.x;
                float dm  = fmaf(lam2, ta.w, ta.z);
                float rdm = fastrcp(dm);
                float lm00 = fmaf(l01, l01, dm) * fastrcp(ta.w);  // l00 + lam2
                float Q = fmaf(em0, fmaf(ta.w, em0, -2.0f*l01*em1), lm00*em1*em1);
                float mu2  = rdm*(lm00*em1 - l01*em0);
                float rlm  = fastrcp(lm00);
                float rv1  = dm * rlm;                // 1/var2
                float lnlm = __logf(lm00);
                float4 ev = emi[CUR ^ 1][pp];         // (sw+ez, 1/sv, sm/sv, 0)
                float lam = rv1 + ev.y;
                float emm = fmaf(mu2, rv1, ev.z);
                float sz  = fmaf(0.5f, fmaf(Q, rdm, -fmaf(mu2*mu2, rv1, lnlm)),
                                 tb.y + z2s + ev.x);
                float* wp = (float*)&pkc4[CUR ^ 1][pp][0] + 6*(ss >> 1) + (ss & 1);
                wp[0] = lam;
                wp[2] = emm;
                wp[4] = sz * TRLN2;
                if (FIN) {
                    float vm = fastrcp(lam);
                    float zm = -0.5f*(LOG2PI + __logf(vm) + emm*emm*vm);
                    scv[ss*NLAB + pp] = sz - zm;      // nsc, feeds logsumexp
                }
            }
        }
        __syncthreads();   // barrier 2: new carries visible to all waves
    };

    int t = 1;
#pragma unroll 1
    for (int it = 0; it < (LSEQ - 2) / 2; ++it) {   // 255 double-steps: t=1..510
        stepf(IC<0>{}, IC<0>{}, t); ++t;
        stepf(IC<1>{}, IC<0>{}, t); ++t;
    }
    stepf(IC<0>{}, IC<1>{}, t);   // t = 511 (FIN: computes zm/nsc -> scv)

    // ---- final logsumexp over 184 component scores (wave 0) ----
    if (tid < 64) {
        float mx = -1e38f;
        for (int i = tid; i < KC; i += 64) mx = fmaxf(mx, scv[i]);
#pragma unroll
        for (int m = 32; m; m >>= 1) mx = fmaxf(mx, __shfl_xor(mx, m, 64));
        float sum = 0.0f;
        for (int i = tid; i < KC; i += 64) sum += __expf(scv[i] - mx);
#pragma unroll
        for (int m = 32; m; m >>= 1) sum += __shfl_xor(sum, m, 64);
        if (tid == 0) out[b] = mx + __logf(sum);
    }
}

extern "C" void kernel_launch(void* const* d_in, const int* in_sizes, int n_in,
                              void* d_out, int out_size, void* d_ws, size_t ws_size,
                              hipStream_t stream) {
    const int*   tokens = (const int*)d_in[0];
    const float* sw     = (const float*)d_in[1];
    const float* sm     = (const float*)d_in[2];
    const float* sv     = (const float*)d_in[3];
    const float* tw     = (const float*)d_in[4];
    const float* tmu    = (const float*)d_in[5];
    const float* tvp    = (const float*)d_in[6];
    float* o = (float*)d_out;
    hipLaunchKernelGGL(lveg_kernel, dim3(64), dim3(BLOCK), 0, stream,
                       tokens, sw, sm, sv, tw, tmu, tvp, o);
}